// Round 19
// baseline (118.762 us; speedup 1.0000x reference)
//
#include <hip/hip_runtime.h>

typedef __bf16 bf16x8 __attribute__((ext_vector_type(8)));
typedef float f32x4 __attribute__((ext_vector_type(4)));
typedef float f32x16 __attribute__((ext_vector_type(16)));
typedef unsigned short u16;
typedef u16 u16x8 __attribute__((ext_vector_type(8)));
typedef u16 u16x4 __attribute__((ext_vector_type(4)));

__device__ __forceinline__ u16 f2bf(float f) {
    union { float f; unsigned u; } x; x.f = f;
    unsigned r = x.u + 0x7fffu + ((x.u >> 16) & 1u);
    return (u16)(r >> 16);
}
__device__ __forceinline__ bf16x8 as_bf16x8(u16x8 v) {
    return __builtin_bit_cast(bf16x8, v);
}
__device__ __forceinline__ void glds16(const void* g, void* l) {
    __builtin_amdgcn_global_load_lds(
        (const __attribute__((address_space(1))) void*)g,
        (__attribute__((address_space(3))) void*)l, 16, 0, 0);
}
// row swizzle in u16-chunk units for 64-u16 rows: s8(r)=(r&7)^((r>>3)&7)
__device__ __forceinline__ int swz(int r) { return (((r & 7) ^ ((r >> 3) & 7)) << 3); }

// fused fp32 -> bf16 for x (524288x8), qkv_w (393216x8), out_w (131072x8)
__global__ __launch_bounds__(256) void cvt3(const float* __restrict__ x,
                                            const float* __restrict__ w,
                                            const float* __restrict__ ow,
                                            u16* __restrict__ x16,
                                            u16* __restrict__ w16,
                                            u16* __restrict__ ow16) {
    int i = blockIdx.x * 256 + threadIdx.x;   // < 1048576
    const float* in; u16* out; int off;
    if (i < 524288)       { in = x;  out = x16;  off = i; }
    else if (i < 917504)  { in = w;  out = w16;  off = i - 524288; }
    else                  { in = ow; out = ow16; off = i - 917504; }
    const float4* p = (const float4*)(in + (size_t)off * 8);
    float4 a = p[0], b = p[1];
    u16x8 o;
    o[0] = f2bf(a.x); o[1] = f2bf(a.y); o[2] = f2bf(a.z); o[3] = f2bf(a.w);
    o[4] = f2bf(b.x); o[5] = f2bf(b.y); o[6] = f2bf(b.z); o[7] = f2bf(b.w);
    *(u16x8*)(out + (size_t)off * 8) = o;
}

// QKV GEMM with fused RoPE + layout epilogue THROUGH LDS (coalesced stores).
// V key-slot permutation for the 32x32-MFMA attention: slot s holds actual
// key k(s) = swap bits 2<->3 of s (self-inverse), so PV A-frag reg order
// matches B-operand slot order with zero data movement.
__global__ __launch_bounds__(256) void gemm_qkv(const u16* __restrict__ A,
                                                const u16* __restrict__ B,
                                                u16* __restrict__ Qb,
                                                u16* __restrict__ Kb,
                                                u16* __restrict__ Vt) {
    __shared__ u16 smem[17408];   // staging [0,16384); epilogue view [128][136]
    const int K = 1024, nbx = 24;
    const int tid = threadIdx.x, lane = tid & 63, wave = tid >> 6;
    const int cpx = gridDim.x >> 3;
    const int nid = (blockIdx.x & 7) * cpx + (blockIdx.x >> 3);
    const int m0 = (nid / nbx) << 7, n0 = (nid % nbx) << 7;
    const int wr = (wave >> 1) << 6, wc = (wave & 1) << 6;
    const int fr = lane & 15, fo = (lane >> 4) << 3;
    const int srow = tid >> 2, scol = (tid & 3) << 3;
    const u16* Ag = A + (size_t)(m0 + srow) * K + scol;
    const u16* Bg = B + (size_t)(n0 + srow) * K + scol;
    u16* AsW = smem + (wave << 9);
    u16* BsW = smem + 8192 + (wave << 9);
    f32x4 acc[4][4] = {};
    const int nsteps = K >> 5;
    glds16(Ag, AsW);
    glds16(Ag + (size_t)64 * K, AsW + 2048);
    glds16(Bg, BsW);
    glds16(Bg + (size_t)64 * K, BsW + 2048);
    int cur = 0;
    for (int s = 0; s < nsteps; ++s) {
        __syncthreads();
        if (s + 1 < nsteps) {
            const u16* Ap = Ag + (s + 1) * 32;
            const u16* Bp = Bg + (s + 1) * 32;
            const int nb = (cur ^ 1) << 12;
            glds16(Ap, AsW + nb);
            glds16(Ap + (size_t)64 * K, AsW + nb + 2048);
            glds16(Bp, BsW + nb);
            glds16(Bp + (size_t)64 * K, BsW + nb + 2048);
        }
        const u16* Ab = smem + (cur << 12);
        const u16* Bb = smem + 8192 + (cur << 12);
        bf16x8 af[4], bfr[4];
        #pragma unroll
        for (int i = 0; i < 4; ++i)
            af[i] = *(const bf16x8*)(Ab + (wr + i * 16 + fr) * 32 + fo);
        #pragma unroll
        for (int i = 0; i < 4; ++i)
            bfr[i] = *(const bf16x8*)(Bb + (wc + i * 16 + fr) * 32 + fo);
        #pragma unroll
        for (int i = 0; i < 4; ++i)
            #pragma unroll
            for (int j = 0; j < 4; ++j)
                acc[i][j] = __builtin_amdgcn_mfma_f32_16x16x32_bf16(af[i], bfr[j], acc[i][j], 0, 0, 0);
        cur ^= 1;
    }
    const int cr = (lane >> 4) << 2, cc = lane & 15;
    const int bb = m0 >> 11, sb = m0 & 2047;
    __syncthreads();   // all waves done with staging LDS before overlay
    if (n0 >= 2048) {
        // ---- V: LDS[c][tile*64 + s(k)]; s(k) = swap bits 2,3 of k (k&3==r) ----
        #pragma unroll
        for (int i = 0; i < 4; ++i) {
            const int sl = wr + i * 16 + cr;        // +r later; k&3==0 here
            const int k = sl & 63;
            const int p0 = ((sl >> 6) << 6)
                         + (k & ~12) | 0;           // base bits
            const int ps = (((sl >> 6) << 6) + (k & ~12))
                         + ((cr & 4) << 1) + ((cr & 8) >> 1);  // swap bits 2,3
            #pragma unroll
            for (int j = 0; j < 4; ++j) {
                const int c = wc + j * 16 + cc;
                u16x4 v4;
                #pragma unroll
                for (int r = 0; r < 4; ++r) v4[r] = f2bf(acc[i][j][r]);
                *(u16x4*)&smem[c * 136 + ps] = v4;
            }
            (void)p0;
        }
        __syncthreads();
        const int c = tid >> 1, hf = tid & 1;
        const int hh = c >> 6, d = c & 63;
        const int h0 = (n0 - 2048) >> 6;
        u16* dst = Vt + (((size_t)(bb * 16 + h0 + hh)) << 17) + ((size_t)d << 11)
                 + sb + (hf << 6);
        const u16* sr = &smem[c * 136 + (hf << 6)];
        #pragma unroll
        for (int q = 0; q < 8; ++q)
            *(u16x8*)(dst + q * 8) = *(const u16x8*)(sr + q * 8);
    } else {
        // ---- Q/K: RoPE in fp32, LDS[s][c], re-read rows -> [b,h,s,64] ----
        const bool isQ = (n0 < 1024);
        const float qs = isQ ? 0.18033688011112042f : 1.0f;   // 0.125*log2e for Q
        const float sgn = (cc & 1) ? 1.f : -1.f;
        #pragma unroll
        for (int j = 0; j < 4; ++j) {
            const int c = wc + j * 16 + cc;
            const int tr = (c & 63) >> 1;
            const float invf = exp2f((float)tr * -0.4152410118609203f)
                             * 0.15915494309189535f;   // 10000^(-2t/64)/(2pi)
            #pragma unroll
            for (int i = 0; i < 4; ++i) {
                #pragma unroll
                for (int r = 0; r < 4; ++r) {
                    const int sl = wr + i * 16 + cr + r;
                    float own  = acc[i][j][r];
                    float part = __shfl_xor(own, 1);
                    float rev  = (float)(sb + sl) * invf;
                    rev -= floorf(rev);
                    float sn = __builtin_amdgcn_sinf(rev);   // sin(2*pi*x)
                    float cs = __builtin_amdgcn_cosf(rev);
                    smem[sl * 136 + c] = f2bf((cs * own + sgn * sn * part) * qs);
                }
            }
        }
        __syncthreads();
        const int sl = tid >> 1, hh = tid & 1;
        const int h0 = (isQ ? n0 : (n0 - 1024)) >> 6;
        u16* Outb = isQ ? Qb : Kb;
        u16* dst = Outb + (((size_t)(bb * 16 + h0 + hh)) << 17)
                 + ((size_t)(sb + sl) << 6);
        const u16* sr = &smem[sl * 136 + (hh << 6)];
        #pragma unroll
        for (int q = 0; q < 8; ++q)
            *(u16x8*)(dst + q * 8) = *(const u16x8*)(sr + q * 8);
    }
}

// out-proj GEMM: C fp32 = A@B^T, 128x128 tile (r15-proven).
__global__ __launch_bounds__(256) void gemm128(const u16* __restrict__ A,
                                               const u16* __restrict__ B,
                                               float* __restrict__ C,
                                               int N, int K, int nbx) {
    __shared__ u16 As[2][4096];
    __shared__ u16 Bs[2][4096];
    const int tid = threadIdx.x, lane = tid & 63, wave = tid >> 6;
    const int cpx = gridDim.x >> 3;
    const int nid = (blockIdx.x & 7) * cpx + (blockIdx.x >> 3);
    const int m0 = (nid / nbx) << 7, n0 = (nid % nbx) << 7;
    const int wr = (wave >> 1) << 6, wc = (wave & 1) << 6;
    const int fr = lane & 15, fo = (lane >> 4) << 3;
    const int srow = tid >> 2, scol = (tid & 3) << 3;
    const u16* Ag = A + (size_t)(m0 + srow) * K + scol;
    const u16* Bg = B + (size_t)(n0 + srow) * K + scol;
    u16* AsW = &As[0][0] + (wave << 9);
    u16* BsW = &Bs[0][0] + (wave << 9);
    f32x4 acc[4][4] = {};
    const int nsteps = K >> 5;
    glds16(Ag, AsW);
    glds16(Ag + (size_t)64 * K, AsW + 2048);
    glds16(Bg, BsW);
    glds16(Bg + (size_t)64 * K, BsW + 2048);
    int cur = 0;
    for (int s = 0; s < nsteps; ++s) {
        __syncthreads();
        if (s + 1 < nsteps) {
            const u16* Ap = Ag + (s + 1) * 32;
            const u16* Bp = Bg + (s + 1) * 32;
            const int nb = (cur ^ 1) << 12;
            glds16(Ap, AsW + nb);
            glds16(Ap + (size_t)64 * K, AsW + nb + 2048);
            glds16(Bp, BsW + nb);
            glds16(Bp + (size_t)64 * K, BsW + nb + 2048);
        }
        const u16* Ab = &As[cur][0];
        const u16* Bb = &Bs[cur][0];
        bf16x8 af[4], bfr[4];
        #pragma unroll
        for (int i = 0; i < 4; ++i)
            af[i] = *(const bf16x8*)(Ab + (wr + i * 16 + fr) * 32 + fo);
        #pragma unroll
        for (int i = 0; i < 4; ++i)
            bfr[i] = *(const bf16x8*)(Bb + (wc + i * 16 + fr) * 32 + fo);
        #pragma unroll
        for (int i = 0; i < 4; ++i)
            #pragma unroll
            for (int j = 0; j < 4; ++j)
                acc[i][j] = __builtin_amdgcn_mfma_f32_16x16x32_bf16(af[i], bfr[j], acc[i][j], 0, 0, 0);
        cur ^= 1;
    }
    const int cr = (lane >> 4) << 2, cc = lane & 15;
    #pragma unroll
    for (int i = 0; i < 4; ++i)
        for (int j = 0; j < 4; ++j)
            for (int r = 0; r < 4; ++r)
                C[(size_t)(m0 + wr + i * 16 + cr + r) * N + (n0 + wc + j * 16 + cc)] =
                    acc[i][j][r];
}

// Causal flash attention with 32x32x16 MFMA: halves LDS b128 reads per unit
// work vs the 16x16 version (the measured dominant cost). NO online max,
// IN-REGISTER P (swapped QK^T: S^T = mfma(K,Q); lane holds q=lane&31 with 16
// key-scores at reg r -> key (r&3)+8(r>>2)+4hi — exactly the PV A-operand reg
// order given V's key axis is bit2<->bit3 swapped, baked into gemm_qkv).
// 512 blocks x 4 waves (qh,kh); block = balanced pair (qt, 31-pr), 33 K-tiles.
// 3-buffer counted-vmcnt(4) pipeline (r12-proven skeleton); dedicated fp32
// combine in 2 rounds (33-word padded slots, conflict-free).
// NOTE: sched_barrier(0) after the raw s_barrier is LOAD-BEARING (see r17).
__global__ __launch_bounds__(256, 2) void attn_causal(const u16* __restrict__ Q,
                                                      const u16* __restrict__ K,
                                                      const u16* __restrict__ Vt,
                                                      u16* __restrict__ O) {
    __shared__ u16 smem[24576];   // 3 bufs x (K 64x64 | V 64x64) u16 = 48 KB
    __shared__ float cmb[4224];   // combine: [qh*64+lane][33] fp32 (conflict-free)
    const int tid = threadIdx.x, lane = tid & 63, wave = tid >> 6;   // wave 0..3
    const int nid = ((blockIdx.x & 7) << 6) + (blockIdx.x >> 3);     // XCD-contiguous
    const int pr = nid & 15, h = (nid >> 4) & 15, b = nid >> 8;
    const size_t base = (size_t)((b << 4) + h) << 17;   // (b*16+h)*2048*64
    const int lq = lane & 31, hi = lane >> 5;
    const int schk = lane & 7, srow8 = lane >> 3;
    const int qh = wave >> 1, kh = wave & 1;
    float* const slot = cmb + (qh * 64 + lane) * 33;
    u16x8 ones_u;
    #pragma unroll
    for (int i = 0; i < 8; ++i) ones_u[i] = 0x3F80;   // bf16 1.0
    const bf16x8 ones = as_bf16x8(ones_u);

    // stage tile t into buf bi: wave stages 16 K rows + 16 V rows (4 glds16),
    // source col pre-swizzled so LDS[r][c] = G[r][c ^ s8(r)*8] with LDS linear.
    auto stage = [&](int t, int bi) {
        #pragma unroll
        for (int g = 0; g < 2; ++g) {
            const int rg = (wave << 4) + (g << 3);
            const int r  = rg + srow8;
            const int ck = (schk ^ srow8 ^ ((2 * wave + g) & 7)) << 3;
            glds16(K  + base + ((size_t)((t << 6) + r) << 6) + ck,
                   &smem[bi * 8192 + (rg << 6)]);
            glds16(Vt + base + ((size_t)r << 11) + (t << 6) + ck,
                   &smem[bi * 8192 + 4096 + (rg << 6)]);
        }
    };

    for (int phase = 0; phase < 2; ++phase) {
        const int qt = phase ? (31 - pr) : pr;
        const int nkt = qt + 1;
        const int qw = (qt << 6) + (qh << 5);   // wave's 32-q base
        const int qg = qw + lq;                 // this lane's global q row
        bf16x8 aq[4];
        {
            const u16* qrow = Q + base + ((size_t)qg << 6) + (hi << 3);
            #pragma unroll
            for (int m = 0; m < 4; ++m)
                aq[m] = as_bf16x8(*(const u16x8*)(qrow + m * 16));
        }
        f32x16 oacc0 = {}, oacc1 = {}, lacc = {};
        stage(0, 0);
        if (nkt > 1) stage(1, 1);
        int cur = 0;
        for (int t = 0; t < nkt; ++t) {
            if (t + 1 < nkt) asm volatile("s_waitcnt vmcnt(4)" ::: "memory");
            else             asm volatile("s_waitcnt vmcnt(0)" ::: "memory");
            __builtin_amdgcn_s_barrier();           // raw: no vmcnt drain
            __builtin_amdgcn_sched_barrier(0);      // pin: nothing crosses
            int nb = cur + 2; if (nb >= 3) nb -= 3;
            if (t + 2 < nkt) stage(t + 2, nb);
            const u16* Kb = smem + cur * 8192;
            const u16* Vb = Kb + 4096;
            const bool diag = (t == nkt - 1);
            // swapped QK^T (32x32x16): A=K rows=keys (kh*32+lq), B=Q cols=q.
            f32x16 sacc = {};
            __builtin_amdgcn_s_setprio(1);
            {
                const int krow = (kh << 5) + lq;
                const int sw = swz(krow);
                #pragma unroll
                for (int m = 0; m < 4; ++m) {
                    bf16x8 bk = *(const bf16x8*)&Kb[krow * 64 +
                                                    (((m << 4) + (hi << 3)) ^ sw)];
                    sacc = __builtin_amdgcn_mfma_f32_32x32x16_bf16(bk, aq[m], sacc, 0, 0, 0);
                }
            }
            __builtin_amdgcn_s_setprio(0);
            // exp2 -> PV A-fragments in register (reg order == operand order)
            bf16x8 pa0, pa1;
            #pragma unroll
            for (int r = 0; r < 8; ++r) {
                float e = exp2f(sacc[r]);
                if (diag) {
                    const int kgl = (t << 6) + (kh << 5) + (r & 3) + ((r >> 2) << 3) + (hi << 2);
                    e = (kgl <= qg) ? e : 0.f;
                }
                pa0[r] = (__bf16)e;
            }
            #pragma unroll
            for (int r = 0; r < 8; ++r) {
                float e = exp2f(sacc[8 + r]);
                if (diag) {
                    const int kgl = (t << 6) + (kh << 5) + 16 + (r & 3) + ((r >> 2) << 3) + (hi << 2);
                    e = (kgl <= qg) ? e : 0.f;
                }
                pa1[r] = (__bf16)e;
            }
            // PV + row-sum: O[q][d] over this wave's 32 keys; V slots pre-perm'd.
            __builtin_amdgcn_s_setprio(1);
            lacc = __builtin_amdgcn_mfma_f32_32x32x16_bf16(pa0, ones, lacc, 0, 0, 0);
            lacc = __builtin_amdgcn_mfma_f32_32x32x16_bf16(pa1, ones, lacc, 0, 0, 0);
            #pragma unroll
            for (int dn = 0; dn < 2; ++dn) {
                const int vrow = (dn << 5) + lq;
                const int sw = swz(vrow);
                bf16x8 bv0 = *(const bf16x8*)&Vb[vrow * 64 +
                                                 (((kh << 5) + (hi << 3)) ^ sw)];
                bf16x8 bv1 = *(const bf16x8*)&Vb[vrow * 64 +
                                                 (((kh << 5) + 16 + (hi << 3)) ^ sw)];
                if (dn == 0) {
                    oacc0 = __builtin_amdgcn_mfma_f32_32x32x16_bf16(pa0, bv0, oacc0, 0, 0, 0);
                    oacc0 = __builtin_amdgcn_mfma_f32_32x32x16_bf16(pa1, bv1, oacc0, 0, 0, 0);
                } else {
                    oacc1 = __builtin_amdgcn_mfma_f32_32x32x16_bf16(pa0, bv0, oacc1, 0, 0, 0);
                    oacc1 = __builtin_amdgcn_mfma_f32_32x32x16_bf16(pa1, bv1, oacc1, 0, 0, 0);
                }
            }
            __builtin_amdgcn_s_setprio(0);
            cur = (cur + 1 == 3) ? 0 : cur + 1;
        }
        // ---- combine kh halves (additive), 2 rounds, dedicated fp32 buffer ----
        __syncthreads();
        if (kh) {
            #pragma unroll
            for (int r = 0; r < 16; ++r) slot[r] = oacc0[r];
            #pragma unroll
            for (int r = 0; r < 16; ++r) slot[16 + r] = lacc[r];
        }
        __syncthreads();
        if (!kh) {
            #pragma unroll
            for (int r = 0; r < 16; ++r) oacc0[r] += slot[r];
            #pragma unroll
            for (int r = 0; r < 16; ++r) lacc[r] += slot[16 + r];
        }
        __syncthreads();
        if (kh) {
            #pragma unroll
            for (int r = 0; r < 16; ++r) slot[r] = oacc1[r];
        }
        __syncthreads();
        if (!kh) {
            #pragma unroll
            for (int r = 0; r < 16; ++r) oacc1[r] += slot[r];
            #pragma unroll
            for (int r = 0; r < 16; ++r) {
                const int q = qw + (r & 3) + ((r >> 2) << 3) + (hi << 2);
                const float iv = 1.f / lacc[r];
                u16* op = O + ((size_t)((b << 11) + q) << 10) + (h << 6) + lq;
                op[0]  = f2bf(oacc0[r] * iv);
                op[32] = f2bf(oacc1[r] * iv);
            }
        }
        __syncthreads();   // before next phase's stage(0,0)
    }
}

extern "C" void kernel_launch(void* const* d_in, const int* in_sizes, int n_in,
                              void* d_out, int out_size, void* d_ws, size_t ws_size,
                              hipStream_t stream) {
    const float* x     = (const float*)d_in[0];   // [2,2048,1024]
    const float* qkv_w = (const float*)d_in[1];   // [3072,1024]
    const float* out_w = (const float*)d_in[2];   // [1024,1024]
    float* out = (float*)d_out;                   // [2,2048,1024] fp32

    char* ws = (char*)d_ws;
    u16* Qb    = (u16*)(ws + 25165824);              // 8388608 B
    u16* Kb    = (u16*)(ws + 33554432);              // 8388608 B
    u16* Vtg   = (u16*)(ws + 41943040);              // 8388608 B (transposed V)
    u16* x16   = (u16*)(ws + 50331648);              // 8388608 B (reused as att16)
    u16* att16 = (u16*)(ws + 50331648);
    u16* w16   = (u16*)(ws + 58720256);              // 6291456 B
    u16* ow16  = (u16*)(ws + 65011712);              // 2097152 B  (total 67108864)

    // 0) fused fp32 -> bf16 converts (one launch)
    cvt3<<<4096, 256, 0, stream>>>(x, qkv_w, out_w, x16, w16, ow16);
    // 1) QKV GEMM + fused RoPE/transpose epilogue -> Qb, Kb, Vtg directly
    gemm_qkv<<<768, 256, 0, stream>>>(x16, w16, Qb, Kb, Vtg);
    // 2) causal flash attention: 512 blocks x 256 thr, 32x32 MFMA
    attn_causal<<<512, 256, 0, stream>>>(Qb, Kb, Vtg, att16);
    // 3) out = att16 @ out_w^T (fp32 out): M=4096, N=1024, K=1024
    gemm128<<<256, 256, 0, stream>>>(att16, ow16, out, 1024, 1024, 8);
}